// Round 1
// baseline (73.440 us; speedup 1.0000x reference)
//
#include <hip/hip_runtime.h>

#define F_ALPHA 0.25f
#define F_EPS 1e-4f

constexpr int B = 4, A = 100000, C = 80, M = 32;
constexpr int APB = 256;     // anchors per block
constexpr int THREADS = 256;

struct WS {
  double cls_sum[B];
  double reg_sum[B];
  unsigned int pos_cnt[B];
};

__global__ __launch_bounds__(THREADS) void focal_main(
    const float* __restrict__ clsfs,   // [B,A,C]
    const float* __restrict__ rgrss,   // [B,A,4]
    const float* __restrict__ ancs,    // [1,A,4]
    const float* __restrict__ annos,   // [B,M,5]
    WS* __restrict__ ws) {
  const int blocks_per_img = (A + APB - 1) / APB;
  const int b = blockIdx.x / blocks_per_img;
  const int ablk = blockIdx.x - b * blocks_per_img;
  const int a0 = ablk * APB;
  const int tid = threadIdx.x;

  __shared__ float s_ann[M * 5];
  __shared__ signed char s_state[APB];   // -2 ignore, -1 negative, >=0 pos label
  __shared__ float s_red[3][THREADS / 64];

  if (tid < M * 5) s_ann[tid] = annos[b * M * 5 + tid];
  __syncthreads();

  float reg_acc = 0.0f;
  int pos_acc = 0;

  // ---- Phase 1: per-anchor IoU argmax + reg loss ----
  {
    const int a = a0 + tid;
    int state = -2;
    if (a < A) {
      const float4 anc = ((const float4*)ancs)[a];
      const float ax1 = anc.x, ay1 = anc.y, ax2 = anc.z, ay2 = anc.w;
      const float area_a = (ax2 - ax1) * (ay2 - ay1);
      float maxiou = -2.0f;
      int maxidx = 0;
      #pragma unroll 8
      for (int m = 0; m < M; ++m) {
        const float bx1 = s_ann[m * 5 + 0], by1 = s_ann[m * 5 + 1];
        const float bx2 = s_ann[m * 5 + 2], by2 = s_ann[m * 5 + 3];
        float iou = -1.0f;
        if (s_ann[m * 5 + 4] != -1.0f) {
          float iw = fmaxf(fminf(ax2, bx2) - fmaxf(ax1, bx1), 0.0f);
          float ih = fmaxf(fminf(ay2, by2) - fmaxf(ay1, by1), 0.0f);
          float inter = iw * ih;
          float area_b = (bx2 - bx1) * (by2 - by1);
          float ua = fmaxf(area_a + area_b - inter, 1e-8f);
          iou = inter / ua;
        }
        if (iou > maxiou) { maxiou = iou; maxidx = m; }
      }
      const bool pos = (maxiou >= 0.5f);
      if (pos) {
        state = (int)s_ann[maxidx * 5 + 4];
        pos_acc = 1;
        const float bx1 = s_ann[maxidx * 5 + 0], by1 = s_ann[maxidx * 5 + 1];
        const float bx2 = s_ann[maxidx * 5 + 2], by2 = s_ann[maxidx * 5 + 3];
        const float ancw = ax2 - ax1, anch = ay2 - ay1;
        const float ancx = ax1 + 0.5f * ancw, ancy = ay1 + 0.5f * anch;
        const float gtw0 = bx2 - bx1, gth0 = by2 - by1;
        const float gtx = bx1 + 0.5f * gtw0, gty = by1 + 0.5f * gth0;
        const float gtw = fmaxf(gtw0, 1.0f), gth = fmaxf(gth0, 1.0f);
        const float t0 = ((gtx - ancx) / ancw) / 0.1f;
        const float t1 = ((gty - ancy) / anch) / 0.1f;
        const float t2 = __logf(gtw / ancw) / 0.2f;
        const float t3 = __logf(gth / anch) / 0.2f;
        const float4 r = ((const float4*)rgrss)[(size_t)b * A + a];
        const float th = 1.0f / 9.0f, hh = 0.5f / 9.0f;
        float d;
        d = fabsf(t0 - r.x); reg_acc += (d <= th) ? 4.5f * d * d : d - hh;
        d = fabsf(t1 - r.y); reg_acc += (d <= th) ? 4.5f * d * d : d - hh;
        d = fabsf(t2 - r.z); reg_acc += (d <= th) ? 4.5f * d * d : d - hh;
        d = fabsf(t3 - r.w); reg_acc += (d <= th) ? 4.5f * d * d : d - hh;
      } else if (maxiou < 0.4f) {
        state = -1;
      }
    }
    s_state[tid] = (signed char)state;
  }
  __syncthreads();

  // ---- Phase 2: classification loss over the block's [APB x C] slab, float4-coalesced ----
  float cls_acc = 0.0f;
  {
    const float* __restrict__ base = clsfs + ((size_t)b * A + a0) * C;
    const int nanch = min(APB, A - a0);
    const int nvec = nanch * C / 4;   // C=80 -> always divisible by 4
    for (int i4 = tid; i4 < nvec; i4 += THREADS) {
      const float4 v = ((const float4*)base)[i4];
      const int e0 = i4 * 4;
      #pragma unroll
      for (int j = 0; j < 4; ++j) {
        const int e = e0 + j;
        const int al = e / C;          // magic-mul div by 80
        const int c = e - al * C;
        const int st = s_state[al];
        if (st != -2) {
          float p = (j == 0) ? v.x : (j == 1) ? v.y : (j == 2) ? v.z : v.w;
          p = fminf(fmaxf(p, F_EPS), 1.0f - F_EPS);
          float l;
          if (st == c) {
            const float q = 1.0f - p;
            l = F_ALPHA * q * q * (-__logf(p));
          } else {
            l = (1.0f - F_ALPHA) * p * p * (-__logf(1.0f - p));
          }
          cls_acc += l;
        }
      }
    }
  }

  // ---- Block reduction ----
  float reg_f = reg_acc, pos_f = (float)pos_acc;
  #pragma unroll
  for (int off = 32; off > 0; off >>= 1) {
    cls_acc += __shfl_down(cls_acc, off);
    reg_f   += __shfl_down(reg_f, off);
    pos_f   += __shfl_down(pos_f, off);
  }
  const int wave = tid >> 6, lane = tid & 63;
  if (lane == 0) {
    s_red[0][wave] = cls_acc;
    s_red[1][wave] = reg_f;
    s_red[2][wave] = pos_f;
  }
  __syncthreads();
  if (tid == 0) {
    float bc = 0.f, br = 0.f, bp = 0.f;
    #pragma unroll
    for (int w = 0; w < THREADS / 64; ++w) {
      bc += s_red[0][w]; br += s_red[1][w]; bp += s_red[2][w];
    }
    atomicAdd(&ws->cls_sum[b], (double)bc);
    atomicAdd(&ws->reg_sum[b], (double)br);
    atomicAdd(&ws->pos_cnt[b], (unsigned int)(int)(bp + 0.5f));
  }
}

__global__ void focal_final(const float* __restrict__ annos,
                            const WS* __restrict__ ws,
                            float* __restrict__ out) {
  if (threadIdx.x == 0) {
    float cls_mean = 0.0f, reg_mean = 0.0f;
    for (int b = 0; b < B; ++b) {
      bool has = false;
      for (int m = 0; m < M; ++m) has = has || (annos[(b * M + m) * 5 + 4] != -1.0f);
      const unsigned int pn = ws->pos_cnt[b];
      float cls = (float)(ws->cls_sum[b] / ((pn > 0) ? (double)pn : 1.0));
      float reg = (pn > 0) ? (float)(ws->reg_sum[b] / ((double)pn * 4.0)) : 0.0f;
      if (!has) { cls = 0.0f; reg = 0.0f; }
      cls_mean += cls;
      reg_mean += reg;
    }
    out[0] = cls_mean * (1.0f / B);
    out[1] = reg_mean * (1.0f / B);
  }
}

extern "C" void kernel_launch(void* const* d_in, const int* in_sizes, int n_in,
                              void* d_out, int out_size, void* d_ws, size_t ws_size,
                              hipStream_t stream) {
  const float* clsfs = (const float*)d_in[0];
  const float* rgrss = (const float*)d_in[1];
  const float* ancs  = (const float*)d_in[2];
  const float* annos = (const float*)d_in[3];
  float* out = (float*)d_out;
  WS* ws = (WS*)d_ws;

  hipMemsetAsync(ws, 0, sizeof(WS), stream);

  const int blocks_per_img = (A + APB - 1) / APB;
  focal_main<<<dim3(B * blocks_per_img), dim3(THREADS), 0, stream>>>(
      clsfs, rgrss, ancs, annos, ws);
  focal_final<<<1, 64, 0, stream>>>(annos, ws, out);
}

// Round 2
// 65.253 us; speedup vs baseline: 1.1255x; 1.1255x over previous
//
#include <hip/hip_runtime.h>

#define F_ALPHA 0.25f
#define F_EPS 1e-4f

constexpr int B = 4, A = 100000, C = 80, M = 32;
constexpr int APB = 256;     // anchors per block
constexpr int THREADS = 256;
constexpr int VPA = C / 4;   // float4 vectors per anchor row = 20

struct WS {
  double cls_sum[B];
  double reg_sum[B];
  unsigned int pos_cnt[B];
};

// f(p) = p^2 * (-log(1-p)) on clamped p; the 0.75 factor is applied once at the end.
__device__ __forceinline__ float fterm(float p) {
  p = fminf(fmaxf(p, F_EPS), 1.0f - F_EPS);
  return p * p * (-__logf(1.0f - p));
}

__device__ __forceinline__ float fquad(float4 v) {
  return fterm(v.x) + fterm(v.y) + fterm(v.z) + fterm(v.w);
}

__global__ __launch_bounds__(THREADS) void focal_main(
    const float* __restrict__ clsfs,   // [B,A,C]
    const float* __restrict__ rgrss,   // [B,A,4]
    const float* __restrict__ ancs,    // [1,A,4]
    const float* __restrict__ annos,   // [B,M,5]
    WS* __restrict__ ws) {
  const int blocks_per_img = (A + APB - 1) / APB;
  const int b = blockIdx.x / blocks_per_img;
  const int ablk = blockIdx.x - b * blocks_per_img;
  const int a0 = ablk * APB;
  const int tid = threadIdx.x;

  __shared__ float s_ann[M * 5];
  __shared__ float s_w[APB];           // 0 = ignore, 1 = contributes
  __shared__ float s_red[3][THREADS / 64];

  if (tid < M * 5) s_ann[tid] = annos[b * M * 5 + tid];
  __syncthreads();

  float reg_acc = 0.0f;
  float corr_acc = 0.0f;   // positive-anchor one-hot correction to cls loss
  int pos_acc = 0;

  // ---- Phase 1: per-anchor IoU argmax, reg loss, one-hot correction ----
  {
    const int a = a0 + tid;
    float w = 0.0f;
    if (a < A) {
      const float4 anc = ((const float4*)ancs)[a];
      const float ax1 = anc.x, ay1 = anc.y, ax2 = anc.z, ay2 = anc.w;
      const float area_a = (ax2 - ax1) * (ay2 - ay1);
      float maxiou = -2.0f;
      int maxidx = 0;
      #pragma unroll
      for (int m = 0; m < M; ++m) {
        const float bx1 = s_ann[m * 5 + 0], by1 = s_ann[m * 5 + 1];
        const float bx2 = s_ann[m * 5 + 2], by2 = s_ann[m * 5 + 3];
        float iou = -1.0f;
        if (s_ann[m * 5 + 4] != -1.0f) {
          float iw = fmaxf(fminf(ax2, bx2) - fmaxf(ax1, bx1), 0.0f);
          float ih = fmaxf(fminf(ay2, by2) - fmaxf(ay1, by1), 0.0f);
          float inter = iw * ih;
          float area_b = (bx2 - bx1) * (by2 - by1);
          float ua = fmaxf(area_a + area_b - inter, 1e-8f);
          iou = inter / ua;
        }
        if (iou > maxiou) { maxiou = iou; maxidx = m; }
      }
      const bool pos = (maxiou >= 0.5f);
      if (pos) {
        const int lbl = (int)s_ann[maxidx * 5 + 4];
        pos_acc = 1;
        w = 1.0f;
        // one-hot correction: replace 0.75*f(p) with 0.25*(1-p)^2*(-log p)
        float p = clsfs[((size_t)b * A + a) * C + lbl];
        p = fminf(fmaxf(p, F_EPS), 1.0f - F_EPS);
        const float q = 1.0f - p;
        corr_acc = 0.25f * q * q * (-__logf(p)) - 0.75f * p * p * (-__logf(q));
        // regression loss
        const float bx1 = s_ann[maxidx * 5 + 0], by1 = s_ann[maxidx * 5 + 1];
        const float bx2 = s_ann[maxidx * 5 + 2], by2 = s_ann[maxidx * 5 + 3];
        const float ancw = ax2 - ax1, anch = ay2 - ay1;
        const float ancx = ax1 + 0.5f * ancw, ancy = ay1 + 0.5f * anch;
        const float gtw0 = bx2 - bx1, gth0 = by2 - by1;
        const float gtx = bx1 + 0.5f * gtw0, gty = by1 + 0.5f * gth0;
        const float gtw = fmaxf(gtw0, 1.0f), gth = fmaxf(gth0, 1.0f);
        const float t0 = ((gtx - ancx) / ancw) / 0.1f;
        const float t1 = ((gty - ancy) / anch) / 0.1f;
        const float t2 = __logf(gtw / ancw) / 0.2f;
        const float t3 = __logf(gth / anch) / 0.2f;
        const float4 r = ((const float4*)rgrss)[(size_t)b * A + a];
        const float th = 1.0f / 9.0f, hh = 0.5f / 9.0f;
        float d;
        d = fabsf(t0 - r.x); reg_acc += (d <= th) ? 4.5f * d * d : d - hh;
        d = fabsf(t1 - r.y); reg_acc += (d <= th) ? 4.5f * d * d : d - hh;
        d = fabsf(t2 - r.z); reg_acc += (d <= th) ? 4.5f * d * d : d - hh;
        d = fabsf(t3 - r.w); reg_acc += (d <= th) ? 4.5f * d * d : d - hh;
      } else if (maxiou < 0.4f) {
        w = 1.0f;   // negative anchor: contributes f(p) on all classes
      }
      // else: ignore anchor, w stays 0
    }
    s_w[tid] = w;
  }
  __syncthreads();

  // ---- Phase 2: branch-free streaming of the [APB x C] slab, 4x float4 batched ----
  float cls_acc = 0.0f;
  {
    const float* __restrict__ base = clsfs + ((size_t)b * A + a0) * C;
    const int nanch = min(APB, A - a0);
    const int nvec = nanch * VPA;    // float4 count; a float4 never crosses an anchor row
    int i4 = tid;
    for (; i4 + 3 * THREADS < nvec; i4 += 4 * THREADS) {
      const float4 v0 = ((const float4*)base)[i4];
      const float4 v1 = ((const float4*)base)[i4 + THREADS];
      const float4 v2 = ((const float4*)base)[i4 + 2 * THREADS];
      const float4 v3 = ((const float4*)base)[i4 + 3 * THREADS];
      const float w0 = s_w[i4 / VPA];
      const float w1 = s_w[(i4 + THREADS) / VPA];
      const float w2 = s_w[(i4 + 2 * THREADS) / VPA];
      const float w3 = s_w[(i4 + 3 * THREADS) / VPA];
      cls_acc += w0 * fquad(v0);
      cls_acc += w1 * fquad(v1);
      cls_acc += w2 * fquad(v2);
      cls_acc += w3 * fquad(v3);
    }
    for (; i4 < nvec; i4 += THREADS) {
      const float4 v = ((const float4*)base)[i4];
      cls_acc += s_w[i4 / VPA] * fquad(v);
    }
  }
  // fold the 0.75 negative-path factor + positive correction
  cls_acc = 0.75f * cls_acc + corr_acc;

  // ---- Block reduction ----
  float reg_f = reg_acc, pos_f = (float)pos_acc;
  #pragma unroll
  for (int off = 32; off > 0; off >>= 1) {
    cls_acc += __shfl_down(cls_acc, off);
    reg_f   += __shfl_down(reg_f, off);
    pos_f   += __shfl_down(pos_f, off);
  }
  const int wave = tid >> 6, lane = tid & 63;
  if (lane == 0) {
    s_red[0][wave] = cls_acc;
    s_red[1][wave] = reg_f;
    s_red[2][wave] = pos_f;
  }
  __syncthreads();
  if (tid == 0) {
    float bc = 0.f, br = 0.f, bp = 0.f;
    #pragma unroll
    for (int w = 0; w < THREADS / 64; ++w) {
      bc += s_red[0][w]; br += s_red[1][w]; bp += s_red[2][w];
    }
    atomicAdd(&ws->cls_sum[b], (double)bc);
    atomicAdd(&ws->reg_sum[b], (double)br);
    atomicAdd(&ws->pos_cnt[b], (unsigned int)(int)(bp + 0.5f));
  }
}

__global__ void focal_final(const float* __restrict__ annos,
                            const WS* __restrict__ ws,
                            float* __restrict__ out) {
  if (threadIdx.x == 0) {
    float cls_mean = 0.0f, reg_mean = 0.0f;
    for (int b = 0; b < B; ++b) {
      bool has = false;
      for (int m = 0; m < M; ++m) has = has || (annos[(b * M + m) * 5 + 4] != -1.0f);
      const unsigned int pn = ws->pos_cnt[b];
      float cls = (float)(ws->cls_sum[b] / ((pn > 0) ? (double)pn : 1.0));
      float reg = (pn > 0) ? (float)(ws->reg_sum[b] / ((double)pn * 4.0)) : 0.0f;
      if (!has) { cls = 0.0f; reg = 0.0f; }
      cls_mean += cls;
      reg_mean += reg;
    }
    out[0] = cls_mean * (1.0f / B);
    out[1] = reg_mean * (1.0f / B);
  }
}

extern "C" void kernel_launch(void* const* d_in, const int* in_sizes, int n_in,
                              void* d_out, int out_size, void* d_ws, size_t ws_size,
                              hipStream_t stream) {
  const float* clsfs = (const float*)d_in[0];
  const float* rgrss = (const float*)d_in[1];
  const float* ancs  = (const float*)d_in[2];
  const float* annos = (const float*)d_in[3];
  float* out = (float*)d_out;
  WS* ws = (WS*)d_ws;

  hipMemsetAsync(ws, 0, sizeof(WS), stream);

  const int blocks_per_img = (A + APB - 1) / APB;
  focal_main<<<dim3(B * blocks_per_img), dim3(THREADS), 0, stream>>>(
      clsfs, rgrss, ancs, annos, ws);
  focal_final<<<1, 64, 0, stream>>>(annos, ws, out);
}